// Round 4
// baseline (66.092 us; speedup 1.0000x reference)
//
#include <hip/hip_runtime.h>

namespace {
constexpr int D = 8;
constexpr int B = 2;
constexpr int N = 2048;
constexpr long long NN = (long long)N * N;
constexpr float ALPHA_P = 0.95f;   // pre-trace decay
constexpr float ALPHA_D = 0.90f;   // post-trace decay
constexpr float WMAX = 1.0f;
}

// native clang vector (accepted by __builtin_nontemporal_*)
typedef float f32x4 __attribute__((ext_vector_type(4)));

// One block per presynaptic row e; 256 threads; each thread owns 4 cols x 2 tiles.
// Sparsity: Xd (pre spikes) gates the depression d-sum -> only ~10% of dmap
// rows are read densely. Xpost (post spikes) gates potentiation -> the full
// 8-deep dmap column gather happens only at ~10% of columns. Both skips are
// bit-exact (skipped terms are exactly zero in the reference einsum).
// This shrinks the L3-resident set (touched dmap/A lines ~133 MB < 256 MB L3)
// so the once-per-call W/output streams stop thrashing it.
__global__ __launch_bounds__(256) void stdp_main(
    const float* __restrict__ Xd,
    const float* __restrict__ Xpost,
    const float* __restrict__ xbar_pre,
    const float* __restrict__ xbar_post,
    const float* __restrict__ W,
    const float* __restrict__ dmap,
    const float* __restrict__ A_p,
    const float* __restrict__ A_d,
    float* __restrict__ W_prev,
    float* __restrict__ W_new,
    float* __restrict__ xbar_pre_new,
    float* __restrict__ xbar_post_new)
{
    const int e = blockIdx.x;
    const int tid = (int)threadIdx.x;
    const long long row = (long long)e * N;

    // ---- folded trace updates (tiny: 18 elems per block) ----
    if (tid < 16) {
        const int i = e * 16 + tid;                       // covers D*B*N = 32768
        xbar_pre_new[i] = ALPHA_P * xbar_pre[i] + (1.0f - ALPHA_P) * Xd[i];
    } else if (tid < 18) {
        const int i = e * 2 + (tid - 16);                 // covers B*N = 4096
        xbar_post_new[i] = ALPHA_D * xbar_post[i] + (1.0f - ALPHA_D) * Xpost[i];
    }

    // ---- block-uniform spike masks + pre-trace scalars ----
    unsigned dm0 = 0, dm1 = 0;
    float xp0[D], xp1[D];
#pragma unroll
    for (int d = 0; d < D; ++d) {
        if (Xd[(size_t)(d * B + 0) * N + e] != 0.0f) dm0 |= 1u << d;
        if (Xd[(size_t)(d * B + 1) * N + e] != 0.0f) dm1 |= 1u << d;
        xp0[d] = xbar_pre[(size_t)(d * B + 0) * N + e];
        xp1[d] = xbar_pre[(size_t)(d * B + 1) * N + e];
    }
    const unsigned um = dm0 | dm1;

#pragma unroll
    for (int it = 0; it < N / (256 * 4); ++it) {
        const int o = it * 1024 + tid * 4;

        // --- depression sums over ACTIVE delays only (wave-uniform loop) ---
        f32x4 s0 = {0.f, 0.f, 0.f, 0.f};
        f32x4 s1 = {0.f, 0.f, 0.f, 0.f};
        unsigned m = um;
        while (m) {
            const int d = __builtin_ctz(m);
            m &= m - 1;
            const f32x4 mv = *reinterpret_cast<const f32x4*>(
                dmap + (size_t)d * NN + row + o);
            if (dm0 & (1u << d)) s0 += mv;   // Xd value is exactly 1.0
            if (dm1 & (1u << d)) s1 += mv;
        }

        // --- potentiation: full 8-deep column gather only at Xpost spikes ---
        const f32x4 xpo0 = *reinterpret_cast<const f32x4*>(Xpost + o);
        const f32x4 xpo1 = *reinterpret_cast<const f32x4*>(Xpost + N + o);
        f32x4 pot0 = {0.f, 0.f, 0.f, 0.f};
        f32x4 pot1 = {0.f, 0.f, 0.f, 0.f};
        f32x4 apv  = {0.f, 0.f, 0.f, 0.f};
#pragma unroll
        for (int j = 0; j < 4; ++j) {
            if (xpo0[j] != 0.0f || xpo1[j] != 0.0f) {
                float p0 = 0.f, p1 = 0.f;
#pragma unroll
                for (int d = 0; d < D; ++d) {
                    const float md = dmap[(size_t)d * NN + row + o + j];
                    p0 = fmaf(xp0[d], md, p0);
                    p1 = fmaf(xp1[d], md, p1);
                }
                pot0[j] = p0;
                pot1[j] = p1;
                apv[j]  = A_p[row + o + j];
            }
        }

        // --- combine & write ---
        const f32x4 xbp0 = *reinterpret_cast<const f32x4*>(xbar_post + o);
        const f32x4 xbp1 = *reinterpret_cast<const f32x4*>(xbar_post + N + o);
        f32x4 adv = {0.f, 0.f, 0.f, 0.f};
        if (um)
            adv = *reinterpret_cast<const f32x4*>(A_d + row + o);

        const f32x4 w0 = __builtin_nontemporal_load(
            reinterpret_cast<const f32x4*>(W + row + o));
        const f32x4 w1 = __builtin_nontemporal_load(
            reinterpret_cast<const f32x4*>(W + NN + row + o));

        f32x4 n0, n1;
#pragma unroll
        for (int j = 0; j < 4; ++j) {
            const float dw0 = xpo0[j] * pot0[j] * apv[j] - xbp0[j] * s0[j] * adv[j];
            const float dw1 = xpo1[j] * pot1[j] * apv[j] - xbp1[j] * s1[j] * adv[j];
            n0[j] = fminf(fmaxf(w0[j] + dw0, 0.0f), WMAX);
            n1[j] = fminf(fmaxf(w1[j] + dw1, 0.0f), WMAX);
        }

        __builtin_nontemporal_store(
            w0, reinterpret_cast<f32x4*>(W_prev + row + o));
        __builtin_nontemporal_store(
            w1, reinterpret_cast<f32x4*>(W_prev + NN + row + o));
        __builtin_nontemporal_store(
            n0, reinterpret_cast<f32x4*>(W_new + row + o));
        __builtin_nontemporal_store(
            n1, reinterpret_cast<f32x4*>(W_new + NN + row + o));
    }
}

extern "C" void kernel_launch(void* const* d_in, const int* in_sizes, int n_in,
                              void* d_out, int out_size, void* d_ws, size_t ws_size,
                              hipStream_t stream) {
    const float* Xd        = (const float*)d_in[0];  // (D,B,N)
    const float* Xpost     = (const float*)d_in[1];  // (B,N)
    const float* xbar_pre  = (const float*)d_in[2];  // (D,B,N)
    const float* xbar_post = (const float*)d_in[3];  // (B,N)
    const float* W         = (const float*)d_in[4];  // (B,N,N)
    const float* dmap      = (const float*)d_in[5];  // (D,N,N)
    const float* A_p       = (const float*)d_in[6];  // (N,N)
    const float* A_d       = (const float*)d_in[7];  // (N,N)

    float* out = (float*)d_out;
    float* W_prev        = out;                              // B*N*N
    float* W_new         = W_prev + (size_t)B * NN;          // B*N*N
    float* xbar_pre_new  = W_new + (size_t)B * NN;           // D*B*N
    float* xbar_post_new = xbar_pre_new + (size_t)D * B * N; // B*N

    stdp_main<<<N, 256, 0, stream>>>(Xd, Xpost, xbar_pre, xbar_post, W, dmap,
                                     A_p, A_d, W_prev, W_new,
                                     xbar_pre_new, xbar_post_new);
}

// Round 5
// 66.050 us; speedup vs baseline: 1.0006x; 1.0006x over previous
//
#include <hip/hip_runtime.h>

namespace {
constexpr int D = 8;
constexpr int B = 2;
constexpr int N = 2048;
constexpr long long NN = (long long)N * N;
constexpr float ALPHA_P = 0.95f;   // pre-trace decay
constexpr float ALPHA_D = 0.90f;   // post-trace decay
constexpr float WMAX = 1.0f;
}

// native clang vector (accepted by __builtin_nontemporal_*)
typedef float f32x4 __attribute__((ext_vector_type(4)));

__device__ __forceinline__ void ld8(const float* p, float* a) {
    const f32x4 v0 = *reinterpret_cast<const f32x4*>(p);
    const f32x4 v1 = *reinterpret_cast<const f32x4*>(p + 4);
#pragma unroll
    for (int j = 0; j < 4; ++j) { a[j] = v0[j]; a[4 + j] = v1[j]; }
}
__device__ __forceinline__ void ld8nt(const float* p, float* a) {
    const f32x4 v0 = __builtin_nontemporal_load(reinterpret_cast<const f32x4*>(p));
    const f32x4 v1 = __builtin_nontemporal_load(reinterpret_cast<const f32x4*>(p) + 1);
#pragma unroll
    for (int j = 0; j < 4; ++j) { a[j] = v0[j]; a[4 + j] = v1[j]; }
}
__device__ __forceinline__ void st8nt(float* p, const float* a) {
    f32x4 v0, v1;
#pragma unroll
    for (int j = 0; j < 4; ++j) { v0[j] = a[j]; v1[j] = a[4 + j]; }
    __builtin_nontemporal_store(v0, reinterpret_cast<f32x4*>(p));
    __builtin_nontemporal_store(v1, reinterpret_cast<f32x4*>(p) + 1);
}

// One block per presynaptic row e; 256 threads x 8 cols = full 2048-col row.
// d-OUTER loop with register accumulators: the block reads dmap plane d's row
// as one contiguous 8 KB burst, one plane at a time (sequential streams ->
// DRAM row-buffer locality), instead of interleaving 8 plane streams.
__global__ __launch_bounds__(256) void stdp_main(
    const float* __restrict__ Xd,
    const float* __restrict__ Xpost,
    const float* __restrict__ xbar_pre,
    const float* __restrict__ xbar_post,
    const float* __restrict__ W,
    const float* __restrict__ dmap,
    const float* __restrict__ A_p,
    const float* __restrict__ A_d,
    float* __restrict__ W_prev,
    float* __restrict__ W_new,
    float* __restrict__ xbar_pre_new,
    float* __restrict__ xbar_post_new)
{
    const int e = blockIdx.x;
    const int tid = (int)threadIdx.x;
    const long long row = (long long)e * N;
    const int o = tid * 8;

    // ---- folded trace updates (18 elems per block) ----
    if (tid < 16) {
        const int i = e * 16 + tid;                       // covers D*B*N = 32768
        xbar_pre_new[i] = ALPHA_P * xbar_pre[i] + (1.0f - ALPHA_P) * Xd[i];
    } else if (tid < 18) {
        const int i = e * 2 + (tid - 16);                 // covers B*N = 4096
        xbar_post_new[i] = ALPHA_D * xbar_post[i] + (1.0f - ALPHA_D) * Xpost[i];
    }

    // ---- per-row d-contraction scalars (wave-uniform) ----
    float xp0[D], xp1[D], xs0[D], xs1[D];
#pragma unroll
    for (int d = 0; d < D; ++d) {
        xp0[d] = xbar_pre[(size_t)(d * B + 0) * N + e];
        xp1[d] = xbar_pre[(size_t)(d * B + 1) * N + e];
        xs0[d] = Xd[(size_t)(d * B + 0) * N + e];
        xs1[d] = Xd[(size_t)(d * B + 1) * N + e];
    }

    // ---- hoist epilogue operands: latency hides under the d-loop ----
    float ap[8], ad[8], xpoA[8], xpoB[8], xbpA[8], xbpB[8], wA[8], wB[8];
    ld8(A_p + row + o, ap);
    ld8(A_d + row + o, ad);
    ld8(Xpost + o, xpoA);
    ld8(Xpost + N + o, xpoB);
    ld8(xbar_post + o, xbpA);
    ld8(xbar_post + N + o, xbpB);
    ld8nt(W + row + o, wA);
    ld8nt(W + NN + row + o, wB);

    // ---- d-outer contraction: one 8 KB plane burst per block per d ----
    float potA[8] = {0}, potB[8] = {0}, depA[8] = {0}, depB[8] = {0};
#pragma unroll
    for (int d = 0; d < D; ++d) {
        float m[8];
        ld8(dmap + (size_t)d * NN + row + o, m);
#pragma unroll
        for (int j = 0; j < 8; ++j) {
            potA[j] = fmaf(xp0[d], m[j], potA[j]);
            potB[j] = fmaf(xp1[d], m[j], potB[j]);
            depA[j] = fmaf(xs0[d], m[j], depA[j]);
            depB[j] = fmaf(xs1[d], m[j], depB[j]);
        }
    }

    // ---- combine & write ----
    float nA[8], nB[8];
#pragma unroll
    for (int j = 0; j < 8; ++j) {
        const float dwA = xpoA[j] * potA[j] * ap[j] - xbpA[j] * depA[j] * ad[j];
        const float dwB = xpoB[j] * potB[j] * ap[j] - xbpB[j] * depB[j] * ad[j];
        nA[j] = fminf(fmaxf(wA[j] + dwA, 0.0f), WMAX);
        nB[j] = fminf(fmaxf(wB[j] + dwB, 0.0f), WMAX);
    }

    st8nt(W_prev + row + o, wA);
    st8nt(W_prev + NN + row + o, wB);
    st8nt(W_new + row + o, nA);
    st8nt(W_new + NN + row + o, nB);
}

extern "C" void kernel_launch(void* const* d_in, const int* in_sizes, int n_in,
                              void* d_out, int out_size, void* d_ws, size_t ws_size,
                              hipStream_t stream) {
    const float* Xd        = (const float*)d_in[0];  // (D,B,N)
    const float* Xpost     = (const float*)d_in[1];  // (B,N)
    const float* xbar_pre  = (const float*)d_in[2];  // (D,B,N)
    const float* xbar_post = (const float*)d_in[3];  // (B,N)
    const float* W         = (const float*)d_in[4];  // (B,N,N)
    const float* dmap      = (const float*)d_in[5];  // (D,N,N)
    const float* A_p       = (const float*)d_in[6];  // (N,N)
    const float* A_d       = (const float*)d_in[7];  // (N,N)

    float* out = (float*)d_out;
    float* W_prev        = out;                              // B*N*N
    float* W_new         = W_prev + (size_t)B * NN;          // B*N*N
    float* xbar_pre_new  = W_new + (size_t)B * NN;           // D*B*N
    float* xbar_post_new = xbar_pre_new + (size_t)D * B * N; // B*N

    stdp_main<<<N, 256, 0, stream>>>(Xd, Xpost, xbar_pre, xbar_post, W, dmap,
                                     A_p, A_d, W_prev, W_new,
                                     xbar_pre_new, xbar_post_new);
}

// Round 6
// 44.821 us; speedup vs baseline: 1.4746x; 1.4736x over previous
//
#include <hip/hip_runtime.h>

namespace {
constexpr int D = 8;
constexpr int B = 2;
constexpr int N = 2048;
constexpr long long NN = (long long)N * N;
constexpr float ALPHA_P = 0.95f;   // pre-trace decay
constexpr float ALPHA_D = 0.90f;   // post-trace decay
constexpr float WMAX = 1.0f;
}

typedef float f32x4 __attribute__((ext_vector_type(4)));

// One block per presynaptic row e; 256 threads; o = it*1024 + tid*4 (dense
// 1KB-per-wave-instruction accesses — R3's proven shape). New: dmap/A_p/A_d
// loads are exec-mask predicated at 16B granularity with exact-zero
// substitution (bit-identical math; skipped values only ever multiply 0).
__global__ __launch_bounds__(256) void stdp_main(
    const float* __restrict__ Xd,
    const float* __restrict__ Xpost,
    const float* __restrict__ xbar_pre,
    const float* __restrict__ xbar_post,
    const float* __restrict__ W,
    const float* __restrict__ dmap,
    const float* __restrict__ A_p,
    const float* __restrict__ A_d,
    float* __restrict__ W_prev,
    float* __restrict__ W_new,
    float* __restrict__ xbar_pre_new,
    float* __restrict__ xbar_post_new)
{
    const int e = blockIdx.x;
    const int tid = (int)threadIdx.x;
    const long long row = (long long)e * N;

    // ---- folded trace updates (18 elems per block) ----
    if (tid < 16) {
        const int i = e * 16 + tid;                       // covers D*B*N = 32768
        xbar_pre_new[i] = ALPHA_P * xbar_pre[i] + (1.0f - ALPHA_P) * Xd[i];
    } else if (tid < 18) {
        const int i = e * 2 + (tid - 16);                 // covers B*N = 4096
        xbar_post_new[i] = ALPHA_D * xbar_post[i] + (1.0f - ALPHA_D) * Xpost[i];
    }

    // ---- per-row d-contraction scalars + active-plane mask (row-uniform) ----
    float xp0[D], xp1[D], xs0[D], xs1[D];
    unsigned um = 0;
#pragma unroll
    for (int d = 0; d < D; ++d) {
        xp0[d] = xbar_pre[(size_t)(d * B + 0) * N + e];
        xp1[d] = xbar_pre[(size_t)(d * B + 1) * N + e];
        xs0[d] = Xd[(size_t)(d * B + 0) * N + e];
        xs1[d] = Xd[(size_t)(d * B + 1) * N + e];
        if (xs0[d] != 0.0f || xs1[d] != 0.0f) um |= 1u << d;
    }

#pragma unroll
    for (int it = 0; it < N / (256 * 4); ++it) {
        const int o = it * 1024 + tid * 4;

        const f32x4 xpo0 = *reinterpret_cast<const f32x4*>(Xpost + o);
        const f32x4 xpo1 = *reinterpret_cast<const f32x4*>(Xpost + N + o);
        const f32x4 xbp0 = *reinterpret_cast<const f32x4*>(xbar_post + o);
        const f32x4 xbp1 = *reinterpret_cast<const f32x4*>(xbar_post + N + o);

        // does this thread's 4-col group have any post spike? (pot needed)
        const bool grp = (xpo0[0] != 0.0f) || (xpo0[1] != 0.0f) ||
                         (xpo0[2] != 0.0f) || (xpo0[3] != 0.0f) ||
                         (xpo1[0] != 0.0f) || (xpo1[1] != 0.0f) ||
                         (xpo1[2] != 0.0f) || (xpo1[3] != 0.0f);

        // W: read once, nontemporal
        const f32x4 w0 = __builtin_nontemporal_load(
            reinterpret_cast<const f32x4*>(W + row + o));
        const f32x4 w1 = __builtin_nontemporal_load(
            reinterpret_cast<const f32x4*>(W + NN + row + o));

        // A_p only where pot can be nonzero; A_d only if row has a pre spike
        f32x4 apv = {0.f, 0.f, 0.f, 0.f};
        if (grp) apv = *reinterpret_cast<const f32x4*>(A_p + row + o);
        f32x4 adv = {0.f, 0.f, 0.f, 0.f};
        if (um)  adv = *reinterpret_cast<const f32x4*>(A_d + row + o);

        // gated dense plane loads + FMA chains (ascending d, as in R1/R3)
        f32x4 pot0 = {0.f,0.f,0.f,0.f}, pot1 = {0.f,0.f,0.f,0.f};
        f32x4 dep0 = {0.f,0.f,0.f,0.f}, dep1 = {0.f,0.f,0.f,0.f};
#pragma unroll
        for (int d = 0; d < D; ++d) {
            f32x4 mv = {0.f, 0.f, 0.f, 0.f};
            if (grp || ((um >> d) & 1u))
                mv = *reinterpret_cast<const f32x4*>(dmap + (size_t)d * NN + row + o);
#pragma unroll
            for (int j = 0; j < 4; ++j) {
                pot0[j] = fmaf(xp0[d], mv[j], pot0[j]);
                pot1[j] = fmaf(xp1[d], mv[j], pot1[j]);
                dep0[j] = fmaf(xs0[d], mv[j], dep0[j]);
                dep1[j] = fmaf(xs1[d], mv[j], dep1[j]);
            }
        }

        f32x4 n0, n1;
#pragma unroll
        for (int j = 0; j < 4; ++j) {
            const float dw0 = xpo0[j] * pot0[j] * apv[j] - xbp0[j] * dep0[j] * adv[j];
            const float dw1 = xpo1[j] * pot1[j] * apv[j] - xbp1[j] * dep1[j] * adv[j];
            n0[j] = fminf(fmaxf(w0[j] + dw0, 0.0f), WMAX);
            n1[j] = fminf(fmaxf(w1[j] + dw1, 0.0f), WMAX);
        }

        // dense, full-line stores (one contiguous 1KB per wave instruction)
        __builtin_nontemporal_store(w0, reinterpret_cast<f32x4*>(W_prev + row + o));
        __builtin_nontemporal_store(w1, reinterpret_cast<f32x4*>(W_prev + NN + row + o));
        __builtin_nontemporal_store(n0, reinterpret_cast<f32x4*>(W_new + row + o));
        __builtin_nontemporal_store(n1, reinterpret_cast<f32x4*>(W_new + NN + row + o));
    }
}

extern "C" void kernel_launch(void* const* d_in, const int* in_sizes, int n_in,
                              void* d_out, int out_size, void* d_ws, size_t ws_size,
                              hipStream_t stream) {
    const float* Xd        = (const float*)d_in[0];  // (D,B,N)
    const float* Xpost     = (const float*)d_in[1];  // (B,N)
    const float* xbar_pre  = (const float*)d_in[2];  // (D,B,N)
    const float* xbar_post = (const float*)d_in[3];  // (B,N)
    const float* W         = (const float*)d_in[4];  // (B,N,N)
    const float* dmap      = (const float*)d_in[5];  // (D,N,N)
    const float* A_p       = (const float*)d_in[6];  // (N,N)
    const float* A_d       = (const float*)d_in[7];  // (N,N)

    float* out = (float*)d_out;
    float* W_prev        = out;                              // B*N*N
    float* W_new         = W_prev + (size_t)B * NN;          // B*N*N
    float* xbar_pre_new  = W_new + (size_t)B * NN;           // D*B*N
    float* xbar_post_new = xbar_pre_new + (size_t)D * B * N; // B*N

    stdp_main<<<N, 256, 0, stream>>>(Xd, Xpost, xbar_pre, xbar_post, W, dmap,
                                     A_p, A_d, W_prev, W_new,
                                     xbar_pre_new, xbar_post_new);
}